// Round 5
// baseline (66.967 us; speedup 1.0000x reference)
//
#include <hip/hip_runtime.h>

#define DIMV 96
#define NCH 24
constexpr int VOX = DIMV * DIMV * DIMV;          // 884736
constexpr int N_CUR = 150000;
constexpr int N_GLB = 200000;
constexpr int N_TGT_LOC = 100000;
constexpr int N_TGT_GLB = 120000;

// ---- output offsets (floats) ----
constexpr size_t OFF_COORDS = 0;
constexpr size_t OFF_CURVOL = 450000;                         // 150000*3
constexpr size_t OFF_GLBVOL = OFF_CURVOL + (size_t)VOX * NCH; // 21,683,664
constexpr size_t OFF_TGTVOL = OFF_GLBVOL + (size_t)VOX * NCH; // 42,917,328
constexpr size_t OFF_VALID  = OFF_TGTVOL + (size_t)VOX;       // 43,802,064
constexpr size_t OFF_VALIDT = OFF_VALID + N_GLB;              // 44,002,064

typedef float v4f __attribute__((ext_vector_type(4)));
typedef int   v4i __attribute__((ext_vector_type(4)));

constexpr int N_COORD4 = (N_CUR * 3) / 4;        // 112500 int4->float4 copies

__device__ __forceinline__ int voxel_of(int x, int y, int z) {
    return (x * DIMV + y) * DIMV + z;
}

// Kernel P: ALL point scatters + coords copy + validt.
//  seg 0 [0, N_CUR):     current winner scatter (w_cur>=0 doubles as occupancy)
//  seg 1 [+N_TGT_GLB):   target-global: valid_target + winner (idx j)
//  seg 2 [+N_TGT_LOC):   target-local: winner (idx j + N_TGT_GLB)
//  seg 3 [+N_GLB):       global in-bounds winner scatter (occupancy gated
//                        voxel-side in k_payload; winner set identical)
//  seg 4 [+N_COORD4):    coords int4 -> float4 copy
__global__ void k_points(const int* __restrict__ cur_coords,
                         const int* __restrict__ tgt_coords_g,
                         const int* __restrict__ tgt_coords_l,
                         const int* __restrict__ glb_coords,
                         const int* __restrict__ origin,
                         int* __restrict__ w_cur,
                         int* __restrict__ w_tgt,
                         int* __restrict__ w_glb,
                         float* __restrict__ validt_out,
                         float* __restrict__ coords_out) {
    int i = blockIdx.x * blockDim.x + threadIdx.x;
    if (i < N_CUR) {
        int x = cur_coords[3 * i], y = cur_coords[3 * i + 1], z = cur_coords[3 * i + 2];
        if ((unsigned)x < DIMV && (unsigned)y < DIMV && (unsigned)z < DIMV)
            atomicMax(&w_cur[voxel_of(x, y, z)], i);   // last-write-wins = max idx
    } else if (i < N_CUR + N_TGT_GLB) {
        int j = i - N_CUR;
        int x = tgt_coords_g[3 * j]     - origin[0];
        int y = tgt_coords_g[3 * j + 1] - origin[1];
        int z = tgt_coords_g[3 * j + 2] - origin[2];
        bool inb = (unsigned)x < DIMV && (unsigned)y < DIMV && (unsigned)z < DIMV;
        validt_out[j] = inb ? 1.0f : 0.0f;
        if (inb) atomicMax(&w_tgt[voxel_of(x, y, z)], j);
    } else if (i < N_CUR + N_TGT_GLB + N_TGT_LOC) {
        int j = i - N_CUR - N_TGT_GLB;
        int x = tgt_coords_l[3 * j], y = tgt_coords_l[3 * j + 1], z = tgt_coords_l[3 * j + 2];
        if ((unsigned)x < DIMV && (unsigned)y < DIMV && (unsigned)z < DIMV)
            atomicMax(&w_tgt[voxel_of(x, y, z)], j + N_TGT_GLB);
    } else if (i < N_CUR + N_TGT_GLB + N_TGT_LOC + N_GLB) {
        int j = i - N_CUR - N_TGT_GLB - N_TGT_LOC;
        int x = glb_coords[3 * j]     - origin[0];
        int y = glb_coords[3 * j + 1] - origin[1];
        int z = glb_coords[3 * j + 2] - origin[2];
        if ((unsigned)x < DIMV && (unsigned)y < DIMV && (unsigned)z < DIMV)
            atomicMax(&w_glb[voxel_of(x, y, z)], j);
    } else if (i < N_CUR + N_TGT_GLB + N_TGT_LOC + N_GLB + N_COORD4) {
        int j = i - N_CUR - N_TGT_GLB - N_TGT_LOC - N_GLB;
        v4i c = *(const v4i*)(cur_coords + 4 * j);
        v4f f = {(float)c.x, (float)c.y, (float)c.z, (float)c.w};
        *((v4f*)coords_out + j) = f;
    }
}

// Kernel Y: point-driven sparse payload over memset defaults.
// Thread (p,q) re-derives p's voxel; the unique winner (w[v]==p) writes its
// 16B chunk. Value reads are address-linear in thread id (fully coalesced);
// only the 16B row-chunk stores are scattered (~14 MB total vs the old
// voxel-driven pass's 173 MB mixed stream at 4.6 TB/s).
//  seg A [0, N_CUR*6):           current rows
//  seg B [+N_GLB*6):             global rows (occupancy-gated) + `valid` output
//  seg C [+N_TGT_GLB+N_TGT_LOC): target tsdf singles
constexpr int SEG_A = N_CUR * 6;                  // 900000
constexpr int SEG_B = N_GLB * 6;                  // 1200000
constexpr int SEG_C = N_TGT_GLB + N_TGT_LOC;      // 220000

__global__ void __launch_bounds__(256) k_payload(
                           const int* __restrict__ w_cur,
                           const int* __restrict__ w_glb,
                           const int* __restrict__ w_tgt,
                           const int* __restrict__ cur_coords,
                           const int* __restrict__ glb_coords,
                           const int* __restrict__ tgt_coords_g,
                           const int* __restrict__ tgt_coords_l,
                           const int* __restrict__ origin,
                           const float* __restrict__ cur_values,
                           const float* __restrict__ glb_values,
                           const float* __restrict__ glb_tsdf,   // [120000]
                           const float* __restrict__ loc_tsdf,   // [100000]
                           float* __restrict__ cur_out,
                           float* __restrict__ glb_out,
                           float* __restrict__ tgt_out,
                           float* __restrict__ valid_out) {
    int i = blockIdx.x * blockDim.x + threadIdx.x;
    if (i < SEG_A) {
        int p = i / 6, q = i - p * 6;
        int x = cur_coords[3 * p], y = cur_coords[3 * p + 1], z = cur_coords[3 * p + 2];
        if ((unsigned)x < DIMV && (unsigned)y < DIMV && (unsigned)z < DIMV) {
            int v = voxel_of(x, y, z);
            if (w_cur[v] == p)
                *(v4f*)(cur_out + (size_t)v * NCH + q * 4) =
                    *(const v4f*)(cur_values + (size_t)p * NCH + q * 4);
        }
    } else if (i < SEG_A + SEG_B) {
        int t = i - SEG_A;
        int p = t / 6, q = t - p * 6;
        int x = glb_coords[3 * p]     - origin[0];
        int y = glb_coords[3 * p + 1] - origin[1];
        int z = glb_coords[3 * p + 2] - origin[2];
        bool inb = (unsigned)x < DIMV && (unsigned)y < DIMV && (unsigned)z < DIMV;
        int cx = min(max(x, 0), DIMV - 1);
        int cy = min(max(y, 0), DIMV - 1);
        int cz = min(max(z, 0), DIMV - 1);
        int v = voxel_of(cx, cy, cz);
        bool occ = w_cur[v] >= 0;
        if (q == 0) valid_out[p] = (inb && occ) ? 1.0f : 0.0f;
        if (inb && occ && w_glb[v] == p)
            *(v4f*)(glb_out + (size_t)v * NCH + q * 4) =
                *(const v4f*)(glb_values + (size_t)p * NCH + q * 4);
    } else if (i < SEG_A + SEG_B + SEG_C) {
        int j = i - SEG_A - SEG_B;
        if (j < N_TGT_GLB) {
            int x = tgt_coords_g[3 * j]     - origin[0];
            int y = tgt_coords_g[3 * j + 1] - origin[1];
            int z = tgt_coords_g[3 * j + 2] - origin[2];
            if ((unsigned)x < DIMV && (unsigned)y < DIMV && (unsigned)z < DIMV) {
                int v = voxel_of(x, y, z);
                if (w_tgt[v] == j) tgt_out[v] = glb_tsdf[j];
            }
        } else {
            int jj = j - N_TGT_GLB;
            int x = tgt_coords_l[3 * jj], y = tgt_coords_l[3 * jj + 1], z = tgt_coords_l[3 * jj + 2];
            if ((unsigned)x < DIMV && (unsigned)y < DIMV && (unsigned)z < DIMV) {
                int v = voxel_of(x, y, z);
                if (w_tgt[v] == j) tgt_out[v] = loc_tsdf[jj];
            }
        }
    }
}

extern "C" void kernel_launch(void* const* d_in, const int* in_sizes, int n_in,
                              void* d_out, int out_size, void* d_ws, size_t ws_size,
                              hipStream_t stream) {
    const int*   cur_coords   = (const int*)d_in[0];
    const float* cur_values   = (const float*)d_in[1];
    const int*   glb_coords   = (const int*)d_in[2];
    const float* glb_values   = (const float*)d_in[3];
    const int*   tgt_coords_l = (const int*)d_in[4];
    const float* tgt_tsdf_l   = (const float*)d_in[5];
    const int*   tgt_coords_g = (const int*)d_in[6];
    const float* tgt_tsdf_g   = (const float*)d_in[7];
    const int*   rel_origin   = (const int*)d_in[8];

    float* out = (float*)d_out;
    int* w_cur = (int*)d_ws;         // [VOX] winner current (>=0 also = occupancy)
    int* w_glb = w_cur + VOX;        // [VOX] winner global (in-bounds, voxel-gated)
    int* w_tgt = w_glb + VOX;        // [VOX] winner target

    const int T = 256;
    auto blocks = [](int n) { return (n + 255) / 256; };

    // 1: winner init to -1 (rocclr fill, plain stores -> L2-resident winners)
    (void)hipMemsetD32Async((hipDeviceptr_t)d_ws, (int)0xFFFFFFFF, (size_t)3 * VOX, stream);

    // 2: ALL point scatters + coords copy + validt
    k_points<<<blocks(N_CUR + N_TGT_GLB + N_TGT_LOC + N_GLB + N_COORD4), T, 0, stream>>>(
        cur_coords, tgt_coords_g, tgt_coords_l, glb_coords, rel_origin,
        w_cur, w_tgt, w_glb, out + OFF_VALIDT, out + OFF_COORDS);

    // 3: default fills at pure-stream rate (rocclr fill = 6.9 TB/s measured):
    //    cur_out + glb_out are contiguous zeros (169.9 MB, one fill);
    //    tgt_out defaults to 1.0f.
    (void)hipMemsetD32Async((hipDeviceptr_t)(out + OFF_CURVOL), 0,
                            OFF_TGTVOL - OFF_CURVOL, stream);
    (void)hipMemsetD32Async((hipDeviceptr_t)(out + OFF_TGTVOL), 0x3f800000,
                            (size_t)VOX, stream);

    // 4: sparse point-driven payload (winner-equality = unique writer) + valid
    k_payload<<<blocks(SEG_A + SEG_B + SEG_C), T, 0, stream>>>(
        w_cur, w_glb, w_tgt, cur_coords, glb_coords, tgt_coords_g, tgt_coords_l,
        rel_origin, cur_values, glb_values, tgt_tsdf_g, tgt_tsdf_l,
        out + OFF_CURVOL, out + OFF_GLBVOL, out + OFF_TGTVOL, out + OFF_VALID);
}

// Round 6
// 56.100 us; speedup vs baseline: 1.1937x; 1.1937x over previous
//
#include <hip/hip_runtime.h>

#define DIMV 96
#define NCH 24
constexpr int VOX = DIMV * DIMV * DIMV;          // 884736
constexpr int N_CUR = 150000;
constexpr int N_GLB = 200000;
constexpr int N_TGT_LOC = 100000;
constexpr int N_TGT_GLB = 120000;

// ---- output offsets (floats) ----
constexpr size_t OFF_COORDS = 0;
constexpr size_t OFF_CURVOL = 450000;                         // 150000*3
constexpr size_t OFF_GLBVOL = OFF_CURVOL + (size_t)VOX * NCH; // 21,683,664
constexpr size_t OFF_TGTVOL = OFF_GLBVOL + (size_t)VOX * NCH; // 42,917,328
constexpr size_t OFF_VALID  = OFF_TGTVOL + (size_t)VOX;       // 43,802,064
constexpr size_t OFF_VALIDT = OFF_VALID + N_GLB;              // 44,002,064

typedef float v4f __attribute__((ext_vector_type(4)));
typedef int   v4i __attribute__((ext_vector_type(4)));

constexpr int N_COORD4 = (N_CUR * 3) / 4;        // 112500 int4->float4 copies
constexpr int NV4_WS   = (3 * VOX) / 4;          // 663552 int4 stores to init winners

__device__ __forceinline__ int voxel_of(int x, int y, int z) {
    return (x * DIMV + y) * DIMV + z;
}

// Kernel I: workspace winner init (-1) + coords int4->float4 copy.
// PLAIN stores (R1: NT init of the atomic-hammered winner arrays cost ~20 us).
__global__ void __launch_bounds__(256) k_init(int* __restrict__ ws,
                                              const int* __restrict__ cur_coords,
                                              float* __restrict__ coords_out) {
    int i = blockIdx.x * blockDim.x + threadIdx.x;
    if (i < NV4_WS) {
        v4i m = {-1, -1, -1, -1};
        *((v4i*)ws + i) = m;
    } else if (i < NV4_WS + N_COORD4) {
        int j = i - NV4_WS;
        v4i c = *(const v4i*)(cur_coords + 4 * j);
        v4f f = {(float)c.x, (float)c.y, (float)c.z, (float)c.w};
        *((v4f*)coords_out + j) = f;
    }
}

// Kernel P: ALL point scatters in one launch. Occupancy gating for global
// points is voxel-side (see k_fill_all): scatter every IN-BOUNDS global
// point; winner sets identical where the fill emits payload.
__global__ void k_points(const int* __restrict__ cur_coords,
                         const int* __restrict__ tgt_coords_g,
                         const int* __restrict__ tgt_coords_l,
                         const int* __restrict__ glb_coords,
                         const int* __restrict__ origin,
                         int* __restrict__ w_cur,
                         int* __restrict__ w_tgt,
                         int* __restrict__ w_glb,
                         float* __restrict__ validt_out) {
    int i = blockIdx.x * blockDim.x + threadIdx.x;
    if (i < N_CUR) {
        int x = cur_coords[3 * i], y = cur_coords[3 * i + 1], z = cur_coords[3 * i + 2];
        if ((unsigned)x < DIMV && (unsigned)y < DIMV && (unsigned)z < DIMV)
            atomicMax(&w_cur[voxel_of(x, y, z)], i);   // last-write-wins = max idx
    } else if (i < N_CUR + N_TGT_GLB) {
        int j = i - N_CUR;
        int x = tgt_coords_g[3 * j]     - origin[0];
        int y = tgt_coords_g[3 * j + 1] - origin[1];
        int z = tgt_coords_g[3 * j + 2] - origin[2];
        bool inb = (unsigned)x < DIMV && (unsigned)y < DIMV && (unsigned)z < DIMV;
        validt_out[j] = inb ? 1.0f : 0.0f;
        if (inb) atomicMax(&w_tgt[voxel_of(x, y, z)], j);
    } else if (i < N_CUR + N_TGT_GLB + N_TGT_LOC) {
        int j = i - N_CUR - N_TGT_GLB;
        int x = tgt_coords_l[3 * j], y = tgt_coords_l[3 * j + 1], z = tgt_coords_l[3 * j + 2];
        if ((unsigned)x < DIMV && (unsigned)y < DIMV && (unsigned)z < DIMV)
            atomicMax(&w_tgt[voxel_of(x, y, z)], j + N_TGT_GLB);
    } else if (i < N_CUR + N_TGT_GLB + N_TGT_LOC + N_GLB) {
        int j = i - N_CUR - N_TGT_GLB - N_TGT_LOC;
        int x = glb_coords[3 * j]     - origin[0];
        int y = glb_coords[3 * j + 1] - origin[1];
        int z = glb_coords[3 * j + 2] - origin[2];
        if ((unsigned)x < DIMV && (unsigned)y < DIMV && (unsigned)z < DIMV)
            atomicMax(&w_glb[voxel_of(x, y, z)], j);
    }
}

// Kernel C: streaming fill of all three volumes + per-point global `valid`.
// R6 A/B: PLAIN stores on the volume streams (was NT). Every near-peak
// writer measured on this chip (rocclr fill 6.85 TB/s, D2D copy 6.3 TB/s)
// uses plain stores; our NT stream ran at ~4.6 TB/s effective. Single
// variable vs the 58.0 us R3 kernel.
__global__ void __launch_bounds__(256) k_fill_all(
                           const int* __restrict__ w_cur,
                           const int* __restrict__ w_glb,
                           const int* __restrict__ w_tgt,
                           const int* __restrict__ glb_coords,
                           const int* __restrict__ origin,
                           const float* __restrict__ cur_values,
                           const float* __restrict__ glb_values,
                           const float* __restrict__ glb_tsdf,   // [120000]
                           const float* __restrict__ loc_tsdf,   // [100000]
                           float* __restrict__ cur_out,
                           float* __restrict__ glb_out,
                           float* __restrict__ tgt_out,
                           float* __restrict__ valid_out) {
    int idx = blockIdx.x * blockDim.x + threadIdx.x;   // N_GLB + VOX*6
    if (idx < N_GLB) {
        int x = glb_coords[3 * idx]     - origin[0];
        int y = glb_coords[3 * idx + 1] - origin[1];
        int z = glb_coords[3 * idx + 2] - origin[2];
        bool inb = (unsigned)x < DIMV && (unsigned)y < DIMV && (unsigned)z < DIMV;
        int cx = min(max(x, 0), DIMV - 1);
        int cy = min(max(y, 0), DIMV - 1);
        int cz = min(max(z, 0), DIMV - 1);
        bool valid = inb && (w_cur[voxel_of(cx, cy, cz)] >= 0);   // occ != 0
        valid_out[idx] = valid ? 1.0f : 0.0f;
        return;
    }
    idx -= N_GLB;
    if (idx >= VOX * 6) return;
    int v = idx / 6, q = idx - v * 6;

    int wc = w_cur[v];
    v4f cval = (v4f){0.f, 0.f, 0.f, 0.f};
    if (wc >= 0) cval = *(const v4f*)(cur_values + (size_t)wc * NCH + q * 4);
    *(v4f*)(cur_out + (size_t)v * NCH + q * 4) = cval;

    int wg = w_glb[v];
    v4f gval = (v4f){0.f, 0.f, 0.f, 0.f};
    if (wg >= 0 && wc >= 0)   // voxel-side occupancy gate (see k_points)
        gval = *(const v4f*)(glb_values + (size_t)wg * NCH + q * 4);
    *(v4f*)(glb_out + (size_t)v * NCH + q * 4) = gval;

    if (q == 0) {
        int wt = w_tgt[v];
        float tval = 1.0f;
        if (wt >= 0) tval = (wt < N_TGT_GLB) ? glb_tsdf[wt] : loc_tsdf[wt - N_TGT_GLB];
        tgt_out[v] = tval;
    }
}

extern "C" void kernel_launch(void* const* d_in, const int* in_sizes, int n_in,
                              void* d_out, int out_size, void* d_ws, size_t ws_size,
                              hipStream_t stream) {
    const int*   cur_coords   = (const int*)d_in[0];
    const float* cur_values   = (const float*)d_in[1];
    const int*   glb_coords   = (const int*)d_in[2];
    const float* glb_values   = (const float*)d_in[3];
    const int*   tgt_coords_l = (const int*)d_in[4];
    const float* tgt_tsdf_l   = (const float*)d_in[5];
    const int*   tgt_coords_g = (const int*)d_in[6];
    const float* tgt_tsdf_g   = (const float*)d_in[7];
    const int*   rel_origin   = (const int*)d_in[8];

    float* out = (float*)d_out;
    int* w_cur = (int*)d_ws;         // [VOX] winner current (>=0 also = occupancy)
    int* w_glb = w_cur + VOX;        // [VOX] winner global (in-bounds, voxel-gated)
    int* w_tgt = w_glb + VOX;        // [VOX] winner target

    const int T = 256;
    auto blocks = [](int n) { return (n + 255) / 256; };

    // 1: winner init to -1 + coords copy (plain stores -> L2-resident winners)
    k_init<<<blocks(NV4_WS + N_COORD4), T, 0, stream>>>(
        (int*)d_ws, cur_coords, out + OFF_COORDS);

    // 2: ALL point scatters (cur, tgt-g + validt, tgt-l, glb in-bounds)
    k_points<<<blocks(N_CUR + N_TGT_GLB + N_TGT_LOC + N_GLB), T, 0, stream>>>(
        cur_coords, tgt_coords_g, tgt_coords_l, glb_coords, rel_origin,
        w_cur, w_tgt, w_glb, out + OFF_VALIDT);

    // 3: streaming fill for all three volumes + global `valid` output
    k_fill_all<<<blocks(N_GLB + VOX * 6), T, 0, stream>>>(
        w_cur, w_glb, w_tgt, glb_coords, rel_origin,
        cur_values, glb_values, tgt_tsdf_g, tgt_tsdf_l,
        out + OFF_CURVOL, out + OFF_GLBVOL, out + OFF_TGTVOL, out + OFF_VALID);
}

// Round 7
// 55.768 us; speedup vs baseline: 1.2008x; 1.0060x over previous
//
#include <hip/hip_runtime.h>

#define DIMV 96
#define NCH 24
constexpr int VOX = DIMV * DIMV * DIMV;          // 884736
constexpr int N_CUR = 150000;
constexpr int N_GLB = 200000;
constexpr int N_TGT_LOC = 100000;
constexpr int N_TGT_GLB = 120000;

// ---- output offsets (floats) ----
constexpr size_t OFF_COORDS = 0;
constexpr size_t OFF_CURVOL = 450000;                         // 150000*3
constexpr size_t OFF_GLBVOL = OFF_CURVOL + (size_t)VOX * NCH; // 21,683,664
constexpr size_t OFF_TGTVOL = OFF_GLBVOL + (size_t)VOX * NCH; // 42,917,328
constexpr size_t OFF_VALID  = OFF_TGTVOL + (size_t)VOX;       // 43,802,064
constexpr size_t OFF_VALIDT = OFF_VALID + N_GLB;              // 44,002,064

typedef float v4f __attribute__((ext_vector_type(4)));
typedef int   v4i __attribute__((ext_vector_type(4)));

constexpr int N_COORD4 = (N_CUR * 3) / 4;        // 112500 int4->float4 copies
constexpr int NV4_WS   = (3 * VOX) / 4;          // 663552 int4 stores to init winners
constexpr int FILL_CHUNKS = VOX * 6;             // 5,308,416 16B chunks (x2 volumes)

__device__ __forceinline__ int voxel_of(int x, int y, int z) {
    return (x * DIMV + y) * DIMV + z;
}

// Kernel I: workspace winner init (-1) + coords int4->float4 copy.
// PLAIN stores (R1: NT init of the atomic-hammered winner arrays cost ~20 us).
__global__ void __launch_bounds__(256) k_init(int* __restrict__ ws,
                                              const int* __restrict__ cur_coords,
                                              float* __restrict__ coords_out) {
    int i = blockIdx.x * blockDim.x + threadIdx.x;
    if (i < NV4_WS) {
        v4i m = {-1, -1, -1, -1};
        *((v4i*)ws + i) = m;
    } else if (i < NV4_WS + N_COORD4) {
        int j = i - NV4_WS;
        v4i c = *(const v4i*)(cur_coords + 4 * j);
        v4f f = {(float)c.x, (float)c.y, (float)c.z, (float)c.w};
        *((v4f*)coords_out + j) = f;
    }
}

// Kernel P: ALL point scatters in one launch. Occupancy gating for global
// points is voxel-side (see k_fill_all): scatter every IN-BOUNDS global
// point; winner sets identical where the fill emits payload.
__global__ void k_points(const int* __restrict__ cur_coords,
                         const int* __restrict__ tgt_coords_g,
                         const int* __restrict__ tgt_coords_l,
                         const int* __restrict__ glb_coords,
                         const int* __restrict__ origin,
                         int* __restrict__ w_cur,
                         int* __restrict__ w_tgt,
                         int* __restrict__ w_glb,
                         float* __restrict__ validt_out) {
    int i = blockIdx.x * blockDim.x + threadIdx.x;
    if (i < N_CUR) {
        int x = cur_coords[3 * i], y = cur_coords[3 * i + 1], z = cur_coords[3 * i + 2];
        if ((unsigned)x < DIMV && (unsigned)y < DIMV && (unsigned)z < DIMV)
            atomicMax(&w_cur[voxel_of(x, y, z)], i);   // last-write-wins = max idx
    } else if (i < N_CUR + N_TGT_GLB) {
        int j = i - N_CUR;
        int x = tgt_coords_g[3 * j]     - origin[0];
        int y = tgt_coords_g[3 * j + 1] - origin[1];
        int z = tgt_coords_g[3 * j + 2] - origin[2];
        bool inb = (unsigned)x < DIMV && (unsigned)y < DIMV && (unsigned)z < DIMV;
        validt_out[j] = inb ? 1.0f : 0.0f;
        if (inb) atomicMax(&w_tgt[voxel_of(x, y, z)], j);
    } else if (i < N_CUR + N_TGT_GLB + N_TGT_LOC) {
        int j = i - N_CUR - N_TGT_GLB;
        int x = tgt_coords_l[3 * j], y = tgt_coords_l[3 * j + 1], z = tgt_coords_l[3 * j + 2];
        if ((unsigned)x < DIMV && (unsigned)y < DIMV && (unsigned)z < DIMV)
            atomicMax(&w_tgt[voxel_of(x, y, z)], j + N_TGT_GLB);
    } else if (i < N_CUR + N_TGT_GLB + N_TGT_LOC + N_GLB) {
        int j = i - N_CUR - N_TGT_GLB - N_TGT_LOC;
        int x = glb_coords[3 * j]     - origin[0];
        int y = glb_coords[3 * j + 1] - origin[1];
        int z = glb_coords[3 * j + 2] - origin[2];
        if ((unsigned)x < DIMV && (unsigned)y < DIMV && (unsigned)z < DIMV)
            atomicMax(&w_glb[voxel_of(x, y, z)], j);
    }
}

// Kernel C (R7): persistent grid-stride fill — the m13-copy / rocclr-fill
// structure. 2048 blocks x 256 threads = 524288 long-lived threads, each
// streaming ~10 chunks, 2 independent chains in flight (manual unroll).
// Plain stores (R6 win). Consecutive lanes handle consecutive (v,q) chunks
// each iteration -> per-instruction coalescing preserved.
__device__ __forceinline__ void fill_chunk(int c,
                           const int* __restrict__ w_cur,
                           const int* __restrict__ w_glb,
                           const int* __restrict__ w_tgt,
                           const float* __restrict__ cur_values,
                           const float* __restrict__ glb_values,
                           const float* __restrict__ glb_tsdf,
                           const float* __restrict__ loc_tsdf,
                           float* __restrict__ cur_out,
                           float* __restrict__ glb_out,
                           float* __restrict__ tgt_out) {
    int v = c / 6, q = c - v * 6;

    int wc = w_cur[v];
    v4f cval = (v4f){0.f, 0.f, 0.f, 0.f};
    if (wc >= 0) cval = *(const v4f*)(cur_values + (size_t)wc * NCH + q * 4);
    *(v4f*)(cur_out + (size_t)v * NCH + q * 4) = cval;

    int wg = w_glb[v];
    v4f gval = (v4f){0.f, 0.f, 0.f, 0.f};
    if (wg >= 0 && wc >= 0)   // voxel-side occupancy gate (see k_points)
        gval = *(const v4f*)(glb_values + (size_t)wg * NCH + q * 4);
    *(v4f*)(glb_out + (size_t)v * NCH + q * 4) = gval;

    if (q == 0) {
        int wt = w_tgt[v];
        float tval = 1.0f;
        if (wt >= 0) tval = (wt < N_TGT_GLB) ? glb_tsdf[wt] : loc_tsdf[wt - N_TGT_GLB];
        tgt_out[v] = tval;
    }
}

__global__ void __launch_bounds__(256) k_fill_all(
                           const int* __restrict__ w_cur,
                           const int* __restrict__ w_glb,
                           const int* __restrict__ w_tgt,
                           const int* __restrict__ glb_coords,
                           const int* __restrict__ origin,
                           const float* __restrict__ cur_values,
                           const float* __restrict__ glb_values,
                           const float* __restrict__ glb_tsdf,   // [120000]
                           const float* __restrict__ loc_tsdf,   // [100000]
                           float* __restrict__ cur_out,
                           float* __restrict__ glb_out,
                           float* __restrict__ tgt_out,
                           float* __restrict__ valid_out) {
    int tid = blockIdx.x * blockDim.x + threadIdx.x;
    int nthreads = gridDim.x * blockDim.x;

    // per-point global `valid` (needs completed w_cur; rides on first 200k threads)
    if (tid < N_GLB) {
        int x = glb_coords[3 * tid]     - origin[0];
        int y = glb_coords[3 * tid + 1] - origin[1];
        int z = glb_coords[3 * tid + 2] - origin[2];
        bool inb = (unsigned)x < DIMV && (unsigned)y < DIMV && (unsigned)z < DIMV;
        int cx = min(max(x, 0), DIMV - 1);
        int cy = min(max(y, 0), DIMV - 1);
        int cz = min(max(z, 0), DIMV - 1);
        bool valid = inb && (w_cur[voxel_of(cx, cy, cz)] >= 0);   // occ != 0
        valid_out[tid] = valid ? 1.0f : 0.0f;
    }

    // grid-stride over all 16B chunks, 2 independent chains per iteration
    for (int c = tid; c < FILL_CHUNKS; c += 2 * nthreads) {
        fill_chunk(c, w_cur, w_glb, w_tgt, cur_values, glb_values,
                   glb_tsdf, loc_tsdf, cur_out, glb_out, tgt_out);
        int c2 = c + nthreads;
        if (c2 < FILL_CHUNKS)
            fill_chunk(c2, w_cur, w_glb, w_tgt, cur_values, glb_values,
                       glb_tsdf, loc_tsdf, cur_out, glb_out, tgt_out);
    }
}

extern "C" void kernel_launch(void* const* d_in, const int* in_sizes, int n_in,
                              void* d_out, int out_size, void* d_ws, size_t ws_size,
                              hipStream_t stream) {
    const int*   cur_coords   = (const int*)d_in[0];
    const float* cur_values   = (const float*)d_in[1];
    const int*   glb_coords   = (const int*)d_in[2];
    const float* glb_values   = (const float*)d_in[3];
    const int*   tgt_coords_l = (const int*)d_in[4];
    const float* tgt_tsdf_l   = (const float*)d_in[5];
    const int*   tgt_coords_g = (const int*)d_in[6];
    const float* tgt_tsdf_g   = (const float*)d_in[7];
    const int*   rel_origin   = (const int*)d_in[8];

    float* out = (float*)d_out;
    int* w_cur = (int*)d_ws;         // [VOX] winner current (>=0 also = occupancy)
    int* w_glb = w_cur + VOX;        // [VOX] winner global (in-bounds, voxel-gated)
    int* w_tgt = w_glb + VOX;        // [VOX] winner target

    const int T = 256;
    auto blocks = [](int n) { return (n + 255) / 256; };

    // 1: winner init to -1 + coords copy (plain stores -> L2-resident winners)
    k_init<<<blocks(NV4_WS + N_COORD4), T, 0, stream>>>(
        (int*)d_ws, cur_coords, out + OFF_COORDS);

    // 2: ALL point scatters (cur, tgt-g + validt, tgt-l, glb in-bounds)
    k_points<<<blocks(N_CUR + N_TGT_GLB + N_TGT_LOC + N_GLB), T, 0, stream>>>(
        cur_coords, tgt_coords_g, tgt_coords_l, glb_coords, rel_origin,
        w_cur, w_tgt, w_glb, out + OFF_VALIDT);

    // 3: persistent grid-stride fill (2048 blocks = full thread capacity)
    k_fill_all<<<2048, T, 0, stream>>>(
        w_cur, w_glb, w_tgt, glb_coords, rel_origin,
        cur_values, glb_values, tgt_tsdf_g, tgt_tsdf_l,
        out + OFF_CURVOL, out + OFF_GLBVOL, out + OFF_TGTVOL, out + OFF_VALID);
}